// Round 1
// baseline (169.277 us; speedup 1.0000x reference)
//
#include <hip/hip_runtime.h>
#include <math.h>

#define NB 32768
#define NK 10
#define ND 512
#define WAVES_PER_BLOCK 4
#define GRID (NB / WAVES_PER_BLOCK)

// One wave (64 lanes) per batch element. Lane l owns floats [8l, 8l+8) of
// each D=512 row (two float4 loads -> fully coalesced 2KB per wave-vector).
__global__ __launch_bounds__(256) void sgns_main(
    const int*   __restrict__ center_ids,
    const int*   __restrict__ context_ids,
    const int*   __restrict__ neg_ids,
    const float* __restrict__ center_emb,
    const float* __restrict__ context_emb,
    float*       __restrict__ partials)
{
    const int tid  = threadIdx.x;
    const int lane = tid & 63;
    const int wave = tid >> 6;
    const int b    = blockIdx.x * WAVES_PER_BLOCK + wave;

    // center vector: loaded once, reused for all 11 dots
    const float4* cvp = (const float4*)(center_emb + (size_t)center_ids[b] * ND);
    const float4 cv0 = cvp[lane * 2 + 0];
    const float4 cv1 = cvp[lane * 2 + 1];

    float part[1 + NK];

    {
        const float4* cp = (const float4*)(context_emb + (size_t)context_ids[b] * ND);
        const float4 x0 = cp[lane * 2 + 0];
        const float4 x1 = cp[lane * 2 + 1];
        part[0] = cv0.x * x0.x + cv0.y * x0.y + cv0.z * x0.z + cv0.w * x0.w
                + cv1.x * x1.x + cv1.y * x1.y + cv1.z * x1.z + cv1.w * x1.w;
    }

#pragma unroll
    for (int k = 0; k < NK; ++k) {
        const float4* np = (const float4*)(context_emb + (size_t)neg_ids[b * NK + k] * ND);
        const float4 x0 = np[lane * 2 + 0];
        const float4 x1 = np[lane * 2 + 1];
        part[1 + k] = cv0.x * x0.x + cv0.y * x0.y + cv0.z * x0.z + cv0.w * x0.w
                    + cv1.x * x1.x + cv1.y * x1.y + cv1.z * x1.z + cv1.w * x1.w;
    }

    // butterfly reduce each of the 11 partial dots across the 64-lane wave
#pragma unroll
    for (int i = 0; i < 1 + NK; ++i) {
        float v = part[i];
#pragma unroll
        for (int off = 32; off > 0; off >>= 1) v += __shfl_xor(v, off, 64);
        part[i] = v;
    }

    // all lanes now hold full dots; compute loss uniformly (no divergence)
    float s = fminf(fmaxf(part[0], -10.0f), 10.0f);
    float loss = log1pf(expf(-s));           // -log_sigmoid(score)
#pragma unroll
    for (int k = 1; k <= NK; ++k) {
        float t = fminf(fmaxf(part[k], -10.0f), 10.0f);
        loss += log1pf(expf(t));             // -log_sigmoid(-neg_score)
    }

    __shared__ float ls[WAVES_PER_BLOCK];
    if (lane == 0) ls[wave] = loss;
    __syncthreads();
    if (tid == 0)
        partials[blockIdx.x] = ls[0] + ls[1] + ls[2] + ls[3];
}

// Deterministic final reduction of the 8192 per-block partials -> mean.
__global__ __launch_bounds__(256) void sgns_finish(
    const float* __restrict__ partials, float* __restrict__ out, int n)
{
    __shared__ float ls[256];
    float s = 0.0f;
    for (int i = threadIdx.x; i < n; i += 256) s += partials[i];
    ls[threadIdx.x] = s;
    __syncthreads();
    for (int w = 128; w > 0; w >>= 1) {
        if (threadIdx.x < w) ls[threadIdx.x] += ls[threadIdx.x + w];
        __syncthreads();
    }
    if (threadIdx.x == 0) out[0] = ls[0] * (1.0f / (float)NB);
}

extern "C" void kernel_launch(void* const* d_in, const int* in_sizes, int n_in,
                              void* d_out, int out_size, void* d_ws, size_t ws_size,
                              hipStream_t stream) {
    const int*   center_ids  = (const int*)d_in[0];
    const int*   context_ids = (const int*)d_in[1];
    const int*   neg_ids     = (const int*)d_in[2];
    const float* center_emb  = (const float*)d_in[3];
    const float* context_emb = (const float*)d_in[4];
    float* out      = (float*)d_out;
    float* partials = (float*)d_ws;   // GRID floats = 32 KB, << ws_size

    sgns_main<<<GRID, 256, 0, stream>>>(center_ids, context_ids, neg_ids,
                                        center_emb, context_emb, partials);
    sgns_finish<<<1, 256, 0, stream>>>(partials, out, GRID);
}